// Round 5
// baseline (578.036 us; speedup 1.0000x reference)
//
#include <hip/hip_runtime.h>

typedef __attribute__((ext_vector_type(8))) short short8;
typedef __attribute__((ext_vector_type(4))) short short4v;
typedef __attribute__((ext_vector_type(4))) float f32x4;

#define DEVI __device__ __forceinline__

// fp32 -> bf16 round-to-nearest-even (finite inputs)
DEVI short f2bf(float x) {
  unsigned int u = __builtin_bit_cast(unsigned int, x);
  u += 0x7fffu + ((u >> 16) & 1u);
  return (short)(u >> 16);
}

// async global->LDS, 16B per lane. LDS dest must be wave-uniform base (+lane*16).
DEVI void g2lds16(const void* g, void* l) {
  __builtin_amdgcn_global_load_lds(
      (const __attribute__((address_space(1))) void*)g,
      (__attribute__((address_space(3))) void*)l, 16, 0, 0);
}

// ---------------------------------------------------------------------------
// Conversion / packing kernels
// ---------------------------------------------------------------------------
__global__ void pack_wqkv(const float* __restrict__ qw, const float* __restrict__ kw,
                          const float* __restrict__ vw, short* __restrict__ W) {
  int gid = blockIdx.x * 256 + threadIdx.x;            // 2560*512 vec4s
  if (gid >= 2560 * 512) return;
  int row = gid >> 9;
  int c4  = (gid & 511) << 2;
  const float* src;
  if (row < 2048)      src = qw + (size_t)row * 2048 + c4;
  else if (row < 2304) src = kw + (size_t)(row - 2048) * 2048 + c4;
  else                 src = vw + (size_t)(row - 2304) * 2048 + c4;
  float4 v = *(const float4*)src;
  short4v o = { f2bf(v.x), f2bf(v.y), f2bf(v.z), f2bf(v.w) };
  *(short4v*)(W + (size_t)row * 2048 + c4) = o;
}

__global__ void pack_bias(const float* __restrict__ qb, const float* __restrict__ kb,
                          const float* __restrict__ vb, float* __restrict__ bias) {
  int i = blockIdx.x * 256 + threadIdx.x;
  if (i >= 2560) return;
  bias[i] = (i < 2048) ? qb[i] : (i < 2304 ? kb[i - 2048] : vb[i - 2304]);
}

__global__ void cvt_bf16(const float* __restrict__ in, short* __restrict__ out, int n4) {
  int gid = blockIdx.x * 256 + threadIdx.x;
  if (gid >= n4) return;
  float4 v = *(const float4*)(in + (size_t)gid * 4);
  short4v o = { f2bf(v.x), f2bf(v.y), f2bf(v.z), f2bf(v.w) };
  *(short4v*)(out + (size_t)gid * 4) = o;
}

// ---------------------------------------------------------------------------
// GEMM: C[M][N] = A[M][K] * Bt[N][K]^T (+bias), bf16 in, fp32 out
// m97 structure: 128x128 tile, BK=64, global_load_lds width=16 staging,
// 4 waves (2x2), each wave 64x64 via 4x4 16x16x32 MFMAs.
// ---------------------------------------------------------------------------
__global__ __launch_bounds__(256) void gemm_bt(const short* __restrict__ A,
                                               const short* __restrict__ Bt,
                                               const float* __restrict__ bias,
                                               float* __restrict__ C,
                                               int M, int N, int K) {
  __shared__ short Asub[128 * 64];   // [row][k] linear
  __shared__ short Bsub[128 * 64];
  const int tid = threadIdx.x;
  const int bn = blockIdx.x, bm = blockIdx.y;
  const int lane = tid & 63, w = tid >> 6;
  const int wm = w >> 1, wn = w & 1;
  const int r15 = lane & 15, kc8 = (lane >> 4) * 8;
  const int lrow = lane >> 3, lcol8 = (lane & 7) * 8;  // staging: 8 rows x 8 lanes/row per 1KB chunk

  f32x4 acc[4][4] = {};

  const short* Ab = A + (size_t)bm * 128 * K;
  const short* Bb = Bt + (size_t)bn * 128 * K;

  for (int kt = 0; kt < K; kt += 64) {
    // stage A and B tiles: 16 chunks each of 1KB (8 rows x 64 bf16); wave w does chunks w*4..w*4+3
#pragma unroll
    for (int i = 0; i < 4; ++i) {
      int chunk = w * 4 + i;
      int row = chunk * 8 + lrow;          // 8 rows per 1KB chunk
      g2lds16(Ab + (size_t)row * K + kt + lcol8, Asub + chunk * 512);
      g2lds16(Bb + (size_t)row * K + kt + lcol8, Bsub + chunk * 512);
    }
    __syncthreads();   // compiler drains vmcnt before barrier -> tiles ready
#pragma unroll
    for (int kk = 0; kk < 2; ++kk) {
      short8 af[4], bfr[4];
#pragma unroll
      for (int mi = 0; mi < 4; ++mi)
        af[mi] = *(const short8*)&Asub[(wm * 64 + mi * 16 + r15) * 64 + kk * 32 + kc8];
#pragma unroll
      for (int ni = 0; ni < 4; ++ni)
        bfr[ni] = *(const short8*)&Bsub[(wn * 64 + ni * 16 + r15) * 64 + kk * 32 + kc8];
#pragma unroll
      for (int mi = 0; mi < 4; ++mi)
#pragma unroll
        for (int ni = 0; ni < 4; ++ni)
          acc[mi][ni] = __builtin_amdgcn_mfma_f32_16x16x32_bf16(af[mi], bfr[ni], acc[mi][ni], 0, 0, 0);
    }
    __syncthreads();   // all waves done reading LDS before next stage
  }

#pragma unroll
  for (int mi = 0; mi < 4; ++mi) {
#pragma unroll
    for (int j = 0; j < 4; ++j) {
      int m = bm * 128 + wm * 64 + mi * 16 + (lane >> 4) * 4 + j;
#pragma unroll
      for (int ni = 0; ni < 4; ++ni) {
        int n = bn * 128 + wn * 64 + ni * 16 + r15;
        float v = acc[mi][ni][j];
        if (bias) v += bias[n];
        C[(size_t)m * N + n] = v;
      }
    }
  }
}

// ---------------------------------------------------------------------------
// RoPE + KV-cache scatter. One block per token (256 threads).
// ---------------------------------------------------------------------------
__global__ __launch_bounds__(256) void rope_scatter(const float* __restrict__ QKV,
                                                    const float* __restrict__ cosT,
                                                    const float* __restrict__ sinT,
                                                    float* __restrict__ buf,
                                                    short* __restrict__ Qbf,
                                                    short* __restrict__ Kbf,
                                                    short* __restrict__ Vt) {
  const int token = blockIdx.x;
  const int tid = threadIdx.x;
  const int b = token >> 10, s = token & 1023;
  const float* qkv = QKV + (size_t)token * 2560;
  constexpr float SC = 0.08838834764831845f * 1.4426950408889634f;  // 1/sqrt(128)*log2(e)

#pragma unroll
  for (int i = 0; i < 4; ++i) {
    int p = tid + 256 * i;
    int hh = p >> 6, dp = p & 63;
    float q1 = qkv[hh * 128 + dp];
    float q2 = qkv[hh * 128 + dp + 64];
    float c  = cosT[s * 128 + dp];
    float sn = sinT[s * 128 + dp];
    float o1 = (q1 * c - q2 * sn) * SC;
    float o2 = (q2 * c + q1 * sn) * SC;
    size_t base = ((size_t)(b * 16 + hh) * 1024 + s) * 128;
    Qbf[base + dp]      = f2bf(o1);
    Qbf[base + dp + 64] = f2bf(o2);
  }
  if (tid < 128) {
    int kvh = tid >> 6, dp = tid & 63;
    float k1 = qkv[2048 + kvh * 128 + dp];
    float k2 = qkv[2048 + kvh * 128 + dp + 64];
    float c  = cosT[s * 128 + dp];
    float sn = sinT[s * 128 + dp];
    float o1 = k1 * c - k2 * sn;
    float o2 = k2 * c + k1 * sn;
    buf[((size_t)token * 4 + kvh) * 128 + dp]      = o1;
    buf[((size_t)token * 4 + kvh) * 128 + dp + 64] = o2;
    size_t kb = ((size_t)(b * 2 + kvh) * 1024 + s) * 128;
    Kbf[kb + dp]      = f2bf(o1);
    Kbf[kb + dp + 64] = f2bf(o2);
  }
  {
    int kvh = tid >> 7, d = tid & 127;
    float v = qkv[2304 + kvh * 128 + d];
    buf[((size_t)token * 4 + 2 + kvh) * 128 + d] = v;
    Vt[((size_t)(b * 2 + kvh) * 128 + d) * 1024 + s] = f2bf(v);
  }
}

// ---------------------------------------------------------------------------
// Flash attention (causal, GQA 8:1). 4 independent waves per block, each wave
// owns one 16-row q tile; KVBLK=64; K/V read direct from global (L2-resident);
// per-wave P_lds region (stride 72), no cross-wave barriers.
// ---------------------------------------------------------------------------
__global__ __launch_bounds__(256) void attn_kernel(const short* __restrict__ Qbf,
                                                   const short* __restrict__ Kbf,
                                                   const short* __restrict__ Vt,
                                                   short* __restrict__ AObf) {
  const int tid = threadIdx.x;
  const int w = tid >> 6, lane = tid & 63;
  const int h = blockIdx.y, b = blockIdx.z;
  const int qt = blockIdx.x * 4 + w;      // 0..63
  const int q0 = qt * 16;
  const int kvh = h >> 3;
  const int r15 = lane & 15, g4 = lane >> 4;
  const float NEG_INF = -__builtin_inff();

  __shared__ short P_all[4][16 * 72];     // per-wave P tile [16 q][64 kv], stride 72
  short* P = &P_all[w][0];

  short8 qf[4];
  const short* Qb = Qbf + ((size_t)(b * 16 + h) * 1024 + q0 + r15) * 128 + g4 * 8;
#pragma unroll
  for (int kc = 0; kc < 4; ++kc) qf[kc] = *(const short8*)(Qb + kc * 32);

  f32x4 oacc[8];
#pragma unroll
  for (int i = 0; i < 8; ++i) oacc[i] = f32x4{0.f, 0.f, 0.f, 0.f};
  float mrow[4] = {NEG_INF, NEG_INF, NEG_INF, NEG_INF};
  float lrow[4] = {0.f, 0.f, 0.f, 0.f};

  const short* Kb = Kbf + (size_t)(b * 2 + kvh) * 1024 * 128;
  const short* Vb = Vt + (size_t)(b * 2 + kvh) * 128 * 1024;

  for (int kv0 = 0; kv0 < q0 + 16; kv0 += 64) {
    // ---- scores: S[16 q][64 kv] in 4 frags ----
    f32x4 s[4];
#pragma unroll
    for (int f = 0; f < 4; ++f) s[f] = f32x4{0.f, 0.f, 0.f, 0.f};
#pragma unroll
    for (int half = 0; half < 2; ++half) {
      short8 kfr[2][4];
#pragma unroll
      for (int kf = 0; kf < 2; ++kf) {
        const short* Kp = Kb + (size_t)(kv0 + half * 32 + kf * 16 + r15) * 128 + g4 * 8;
#pragma unroll
        for (int kc = 0; kc < 4; ++kc) kfr[kf][kc] = *(const short8*)(Kp + kc * 32);
      }
#pragma unroll
      for (int kf = 0; kf < 2; ++kf)
#pragma unroll
        for (int kc = 0; kc < 4; ++kc)
          s[half * 2 + kf] = __builtin_amdgcn_mfma_f32_16x16x32_bf16(qf[kc], kfr[kf][kc], s[half * 2 + kf], 0, 0, 0);
    }
    if (kv0 + 63 > q0) {  // causal mask in boundary tile
#pragma unroll
      for (int f = 0; f < 4; ++f) {
        int kvi = kv0 + f * 16 + r15;
#pragma unroll
        for (int j = 0; j < 4; ++j)
          if (kvi > q0 + g4 * 4 + j) s[f][j] = NEG_INF;
      }
    }
    // ---- online softmax (per q row: reduce over 4 frags + 16 r15 lanes) ----
#pragma unroll
    for (int j = 0; j < 4; ++j) {
      float tmax = fmaxf(fmaxf(s[0][j], s[1][j]), fmaxf(s[2][j], s[3][j]));
      tmax = fmaxf(tmax, __shfl_xor(tmax, 1));
      tmax = fmaxf(tmax, __shfl_xor(tmax, 2));
      tmax = fmaxf(tmax, __shfl_xor(tmax, 4));
      tmax = fmaxf(tmax, __shfl_xor(tmax, 8));
      float mnew = fmaxf(mrow[j], tmax);
      float fac = exp2f(mrow[j] - mnew);
      float p0 = exp2f(s[0][j] - mnew);
      float p1 = exp2f(s[1][j] - mnew);
      float p2 = exp2f(s[2][j] - mnew);
      float p3 = exp2f(s[3][j] - mnew);
      float rs = (p0 + p1) + (p2 + p3);
      rs += __shfl_xor(rs, 1);
      rs += __shfl_xor(rs, 2);
      rs += __shfl_xor(rs, 4);
      rs += __shfl_xor(rs, 8);
      lrow[j] = lrow[j] * fac + rs;
      mrow[j] = mnew;
#pragma unroll
      for (int di = 0; di < 8; ++di) oacc[di][j] *= fac;
      int qr = (g4 * 4 + j) * 72 + r15;
      P[qr]      = f2bf(p0);
      P[qr + 16] = f2bf(p1);
      P[qr + 32] = f2bf(p2);
      P[qr + 48] = f2bf(p3);
    }
    // wave-local LDS ordering (no cross-wave dependency -> no barrier)
    asm volatile("s_waitcnt lgkmcnt(0)" ::: "memory");
    __builtin_amdgcn_sched_barrier(0);
    // ---- PV: O[16 q][128 d] += P[16][64] * V[64][128] ----
#pragma unroll
    for (int half = 0; half < 2; ++half) {
      short8 pa = *(const short8*)&P[r15 * 72 + half * 32 + g4 * 8];
      const short* V0 = Vb + (size_t)r15 * 1024 + kv0 + half * 32 + g4 * 8;
#pragma unroll
      for (int di = 0; di < 8; ++di) {
        short8 vf = *(const short8*)(V0 + (size_t)di * 16 * 1024);
        oacc[di] = __builtin_amdgcn_mfma_f32_16x16x32_bf16(pa, vf, oacc[di], 0, 0, 0);
      }
    }
  }

  short* O = AObf + ((size_t)b * 1024 + q0) * 2048 + h * 128;
#pragma unroll
  for (int j = 0; j < 4; ++j) {
    float inv = 1.0f / lrow[j];
    int rowg = g4 * 4 + j;
#pragma unroll
    for (int di = 0; di < 8; ++di)
      O[(size_t)rowg * 2048 + di * 16 + r15] = f2bf(oacc[di][j] * inv);
  }
}

// ---------------------------------------------------------------------------
// Launch
// ---------------------------------------------------------------------------
extern "C" void kernel_launch(void* const* d_in, const int* in_sizes, int n_in,
                              void* d_out, int out_size, void* d_ws, size_t ws_size,
                              hipStream_t stream) {
  (void)in_sizes; (void)n_in; (void)out_size; (void)ws_size;
  const float* x    = (const float*)d_in[0];
  const float* q_w  = (const float*)d_in[1];
  const float* q_b  = (const float*)d_in[2];
  const float* k_w  = (const float*)d_in[3];
  const float* k_b  = (const float*)d_in[4];
  const float* v_w  = (const float*)d_in[5];
  const float* v_b  = (const float*)d_in[6];
  const float* o_w  = (const float*)d_in[7];
  const float* cosT = (const float*)d_in[8];
  const float* sinT = (const float*)d_in[9];
  const float* kvbuf = (const float*)d_in[10];
  // d_in[11] = select_index: arange(B*S) -> identity row mapping

  float* out = (float*)d_out;                        // 4*1024*2048 fp32
  float* buf = out + (size_t)4 * 1024 * 2048;        // 8192*4*128 fp32

  char* ws = (char*)d_ws;
  short* Wqkv = (short*)(ws);                        // 10,485,760 B
  short* Wo   = (short*)(ws + 10485760);             //  8,388,608 B
  float* bias = (float*)(ws + 18874368);             // 2560 fp32
  short* Xbf  = (short*)(ws + 18884608);             // 16,777,216 B
  float* QKVf = (float*)(ws + 35661824);             // 41,943,040 B
  short* Kbf  = (short*)(ws + 77604864);             // 2,097,152 B
  short* Vt   = (short*)(ws + 79702016);             // 2,097,152 B
  short* Qbf  = Xbf;                                 // alias: x consumed by gemm1
  short* AObf = (short*)QKVf;                        // alias: QKVf consumed by rope

  hipMemcpyAsync(buf, kvbuf, (size_t)4194304 * 4, hipMemcpyDeviceToDevice, stream);

  pack_wqkv<<<5120, 256, 0, stream>>>(q_w, k_w, v_w, Wqkv);
  pack_bias<<<10, 256, 0, stream>>>(q_b, k_b, v_b, bias);
  cvt_bf16<<<8192, 256, 0, stream>>>(x, Xbf, 2097152);
  cvt_bf16<<<4096, 256, 0, stream>>>(o_w, Wo, 1048576);

  gemm_bt<<<dim3(20, 32), 256, 0, stream>>>(Xbf, Wqkv, bias, QKVf, 4096, 2560, 2048);
  rope_scatter<<<4096, 256, 0, stream>>>(QKVf, cosT, sinT, buf, Qbf, Kbf, Vt);
  attn_kernel<<<dim3(16, 16, 4), 256, 0, stream>>>(Qbf, Kbf, Vt, AObf);
  gemm_bt<<<dim3(16, 32), 256, 0, stream>>>(AObf, Wo, nullptr, out, 4096, 2048, 2048);
}

// Round 6
// 390.367 us; speedup vs baseline: 1.4807x; 1.4807x over previous
//
#include <hip/hip_runtime.h>

typedef __attribute__((ext_vector_type(8))) short short8;
typedef __attribute__((ext_vector_type(4))) short short4v;
typedef __attribute__((ext_vector_type(4))) float f32x4;
typedef __attribute__((ext_vector_type(16))) float f32x16;
typedef __attribute__((ext_vector_type(2))) int iv2;
typedef __attribute__((ext_vector_type(4))) int iv4;

#define DEVI __device__ __forceinline__

// fp32 -> bf16 round-to-nearest-even (finite inputs)
DEVI short f2bf(float x) {
  unsigned int u = __builtin_bit_cast(unsigned int, x);
  u += 0x7fffu + ((u >> 16) & 1u);
  return (short)(u >> 16);
}

// async global->LDS, 16B per lane. LDS dest must be wave-uniform base (+lane*16).
DEVI void g2lds16(const void* g, void* l) {
  __builtin_amdgcn_global_load_lds(
      (const __attribute__((address_space(1))) void*)g,
      (__attribute__((address_space(3))) void*)l, 16, 0, 0);
}

// ---------------------------------------------------------------------------
// Conversion / packing kernels
// ---------------------------------------------------------------------------
__global__ void pack_wqkv(const float* __restrict__ qw, const float* __restrict__ kw,
                          const float* __restrict__ vw, short* __restrict__ W) {
  int gid = blockIdx.x * 256 + threadIdx.x;            // 2560*512 vec4s
  if (gid >= 2560 * 512) return;
  int row = gid >> 9;
  int c4  = (gid & 511) << 2;
  const float* src;
  if (row < 2048)      src = qw + (size_t)row * 2048 + c4;
  else if (row < 2304) src = kw + (size_t)(row - 2048) * 2048 + c4;
  else                 src = vw + (size_t)(row - 2304) * 2048 + c4;
  float4 v = *(const float4*)src;
  short4v o = { f2bf(v.x), f2bf(v.y), f2bf(v.z), f2bf(v.w) };
  *(short4v*)(W + (size_t)row * 2048 + c4) = o;
}

__global__ void pack_bias(const float* __restrict__ qb, const float* __restrict__ kb,
                          const float* __restrict__ vb, float* __restrict__ bias) {
  int i = blockIdx.x * 256 + threadIdx.x;
  if (i >= 2560) return;
  bias[i] = (i < 2048) ? qb[i] : (i < 2304 ? kb[i - 2048] : vb[i - 2304]);
}

__global__ void cvt_bf16(const float* __restrict__ in, short* __restrict__ out, int n4) {
  int gid = blockIdx.x * 256 + threadIdx.x;
  if (gid >= n4) return;
  float4 v = *(const float4*)(in + (size_t)gid * 4);
  short4v o = { f2bf(v.x), f2bf(v.y), f2bf(v.z), f2bf(v.w) };
  *(short4v*)(out + (size_t)gid * 4) = o;
}

// ---------------------------------------------------------------------------
// GEMM: C[M][N] = A[M][K] * Bt[N][K]^T (+bias), bf16 in, fp32 out
// m97 structure: 128x128 tile, BK=64, global_load_lds width=16 staging.
// ---------------------------------------------------------------------------
__global__ __launch_bounds__(256) void gemm_bt(const short* __restrict__ A,
                                               const short* __restrict__ Bt,
                                               const float* __restrict__ bias,
                                               float* __restrict__ C,
                                               int M, int N, int K) {
  __shared__ short Asub[128 * 64];   // [row][k] linear
  __shared__ short Bsub[128 * 64];
  const int tid = threadIdx.x;
  const int bn = blockIdx.x, bm = blockIdx.y;
  const int lane = tid & 63, w = tid >> 6;
  const int wm = w >> 1, wn = w & 1;
  const int r15 = lane & 15, kc8 = (lane >> 4) * 8;
  const int lrow = lane >> 3, lcol8 = (lane & 7) * 8;  // 8 rows x 8 lanes/row per 1KB chunk

  f32x4 acc[4][4] = {};

  const short* Ab = A + (size_t)bm * 128 * K;
  const short* Bb = Bt + (size_t)bn * 128 * K;

  for (int kt = 0; kt < K; kt += 64) {
#pragma unroll
    for (int i = 0; i < 4; ++i) {
      int chunk = w * 4 + i;
      int row = chunk * 8 + lrow;          // 8 rows per 1KB chunk
      g2lds16(Ab + (size_t)row * K + kt + lcol8, Asub + chunk * 512);
      g2lds16(Bb + (size_t)row * K + kt + lcol8, Bsub + chunk * 512);
    }
    __syncthreads();
#pragma unroll
    for (int kk = 0; kk < 2; ++kk) {
      short8 af[4], bfr[4];
#pragma unroll
      for (int mi = 0; mi < 4; ++mi)
        af[mi] = *(const short8*)&Asub[(wm * 64 + mi * 16 + r15) * 64 + kk * 32 + kc8];
#pragma unroll
      for (int ni = 0; ni < 4; ++ni)
        bfr[ni] = *(const short8*)&Bsub[(wn * 64 + ni * 16 + r15) * 64 + kk * 32 + kc8];
#pragma unroll
      for (int mi = 0; mi < 4; ++mi)
#pragma unroll
        for (int ni = 0; ni < 4; ++ni)
          acc[mi][ni] = __builtin_amdgcn_mfma_f32_16x16x32_bf16(af[mi], bfr[ni], acc[mi][ni], 0, 0, 0);
    }
    __syncthreads();
  }

#pragma unroll
  for (int mi = 0; mi < 4; ++mi) {
#pragma unroll
    for (int j = 0; j < 4; ++j) {
      int m = bm * 128 + wm * 64 + mi * 16 + (lane >> 4) * 4 + j;
#pragma unroll
      for (int ni = 0; ni < 4; ++ni) {
        int n = bn * 128 + wn * 64 + ni * 16 + r15;
        float v = acc[mi][ni][j];
        if (bias) v += bias[n];
        C[(size_t)m * N + n] = v;
      }
    }
  }
}

// ---------------------------------------------------------------------------
// RoPE + KV-cache scatter. One block per token (256 threads).
// ---------------------------------------------------------------------------
__global__ __launch_bounds__(256) void rope_scatter(const float* __restrict__ QKV,
                                                    const float* __restrict__ cosT,
                                                    const float* __restrict__ sinT,
                                                    float* __restrict__ buf,
                                                    short* __restrict__ Qbf,
                                                    short* __restrict__ Kbf,
                                                    short* __restrict__ Vt) {
  const int token = blockIdx.x;
  const int tid = threadIdx.x;
  const int b = token >> 10, s = token & 1023;
  const float* qkv = QKV + (size_t)token * 2560;
  constexpr float SC = 0.08838834764831845f * 1.4426950408889634f;  // 1/sqrt(128)*log2(e)

#pragma unroll
  for (int i = 0; i < 4; ++i) {
    int p = tid + 256 * i;
    int hh = p >> 6, dp = p & 63;
    float q1 = qkv[hh * 128 + dp];
    float q2 = qkv[hh * 128 + dp + 64];
    float c  = cosT[s * 128 + dp];
    float sn = sinT[s * 128 + dp];
    float o1 = (q1 * c - q2 * sn) * SC;
    float o2 = (q2 * c + q1 * sn) * SC;
    size_t base = ((size_t)(b * 16 + hh) * 1024 + s) * 128;
    Qbf[base + dp]      = f2bf(o1);
    Qbf[base + dp + 64] = f2bf(o2);
  }
  if (tid < 128) {
    int kvh = tid >> 6, dp = tid & 63;
    float k1 = qkv[2048 + kvh * 128 + dp];
    float k2 = qkv[2048 + kvh * 128 + dp + 64];
    float c  = cosT[s * 128 + dp];
    float sn = sinT[s * 128 + dp];
    float o1 = k1 * c - k2 * sn;
    float o2 = k2 * c + k1 * sn;
    buf[((size_t)token * 4 + kvh) * 128 + dp]      = o1;
    buf[((size_t)token * 4 + kvh) * 128 + dp + 64] = o2;
    size_t kb = ((size_t)(b * 2 + kvh) * 1024 + s) * 128;
    Kbf[kb + dp]      = f2bf(o1);
    Kbf[kb + dp + 64] = f2bf(o2);
  }
  {
    int kvh = tid >> 7, d = tid & 127;
    float v = qkv[2304 + kvh * 128 + d];
    buf[((size_t)token * 4 + 2 + kvh) * 128 + d] = v;
    Vt[((size_t)(b * 2 + kvh) * 128 + d) * 1024 + s] = f2bf(v);
  }
}

// ---------------------------------------------------------------------------
// Flash attention, swapped-QK^T 32x32 structure (m214/T12 style).
// One wave per 32-row q-tile; wave pairing {t, 31-t} -> uniform 33 KV-iters.
// ST = mfma(K,Q): lane holds S^T[kv(16 regs)][q=lane&31] -> in-register
// softmax (tree + one shfl_xor(32)); P packed bf16 + permlane32_swap feeds
// PV's B operand; OT = mfma(V^T, P^T) accumulates O^T in registers.
// No LDS in the main loop -> loads freely hoistable by the compiler.
// ---------------------------------------------------------------------------
__global__ __launch_bounds__(256) void attn_kernel(const short* __restrict__ Qbf,
                                                   const short* __restrict__ Kbf,
                                                   const short* __restrict__ Vt,
                                                   short* __restrict__ AObf) {
  const int tid = threadIdx.x;
  const int w = tid >> 6, lane = tid & 63;
  const int h = blockIdx.y, b = blockIdx.z;
  const int pr = blockIdx.x * 2 + (w >> 1);     // pair index 0..15
  const int tile = (w & 1) ? (31 - pr) : pr;    // q-tile 0..31 (32 rows each)
  const int kvh = h >> 3;
  const int l31 = lane & 31, hi = lane >> 5;
  const float NEG_INF = -__builtin_inff();

  __shared__ short Olds_all[4][32 * 132];       // per-wave O transpose buffer
  short* Olds = &Olds_all[w][0];

  const short* Kb = Kbf + (size_t)(b * 2 + kvh) * 1024 * 128;
  const short* Vb = Vt + (size_t)(b * 2 + kvh) * 128 * 1024;

  const int q0 = tile * 32;

  // Q fragments (B-operand): lane holds Q[q0+l31][kc*16 + hi*8 + 0..7]
  short8 qb[8];
  const short* Qp = Qbf + ((size_t)(b * 16 + h) * 1024 + q0 + l31) * 128 + hi * 8;
#pragma unroll
  for (int kc = 0; kc < 8; ++kc) qb[kc] = *(const short8*)(Qp + kc * 16);

  f32x16 ot[4];
#pragma unroll
  for (int i = 0; i < 4; ++i)
#pragma unroll
    for (int r = 0; r < 16; ++r) ot[i][r] = 0.f;
  float mrow = NEG_INF, lrow = 0.f;

  for (int kv0 = 0; kv0 <= q0; kv0 += 32) {
    // ---- ST[kv][q] = K Q^T (swapped): 8 MFMAs over d ----
    const short* Kp = Kb + (size_t)(kv0 + l31) * 128 + hi * 8;
    f32x16 st;
#pragma unroll
    for (int r = 0; r < 16; ++r) st[r] = 0.f;
#pragma unroll
    for (int kc = 0; kc < 8; ++kc) {
      short8 ka = *(const short8*)(Kp + kc * 16);
      st = __builtin_amdgcn_mfma_f32_32x32x16_bf16(ka, qb[kc], st, 0, 0, 0);
    }
    // ---- V^T fragments (A-operand of PV), independent of softmax ----
    short8 va[8];
#pragma unroll
    for (int dblk = 0; dblk < 4; ++dblk) {
      const short* Vp = Vb + (size_t)(dblk * 32 + l31) * 1024 + kv0 + hi * 8;
      va[dblk * 2]     = *(const short8*)(Vp);
      va[dblk * 2 + 1] = *(const short8*)(Vp + 16);
    }
    // ---- causal mask (diagonal tile only) ----
    if (kv0 == q0) {
      int thr = l31 - 4 * hi;   // mask where (r&3)+8*(r>>2) > thr
#pragma unroll
      for (int r = 0; r < 16; ++r) {
        int kvc = (r & 3) + 8 * (r >> 2);
        if (kvc > thr) st[r] = NEG_INF;
      }
    }
    // ---- online softmax, per lane (q = l31; kv split across lane^32) ----
    float a0 = fmaxf(st[0], st[1]),  a1 = fmaxf(st[2], st[3]);
    float a2 = fmaxf(st[4], st[5]),  a3 = fmaxf(st[6], st[7]);
    float a4 = fmaxf(st[8], st[9]),  a5 = fmaxf(st[10], st[11]);
    float a6 = fmaxf(st[12], st[13]), a7 = fmaxf(st[14], st[15]);
    float b0 = fmaxf(a0, a1), b1 = fmaxf(a2, a3);
    float b2 = fmaxf(a4, a5), b3 = fmaxf(a6, a7);
    float tmax = fmaxf(fmaxf(b0, b1), fmaxf(b2, b3));
    tmax = fmaxf(tmax, __shfl_xor(tmax, 32));
    // defer-max (T13): rescale only if some lane's max grew past m+8
    if (__ballot(tmax > mrow + 8.f) != 0ull) {
      float mnew = fmaxf(mrow, tmax);
      float fac = exp2f(mrow - mnew);
      lrow *= fac;
#pragma unroll
      for (int i = 0; i < 4; ++i)
#pragma unroll
        for (int r = 0; r < 16; ++r) ot[i][r] *= fac;
      mrow = mnew;
    }
    float pexp[16];
#pragma unroll
    for (int r = 0; r < 16; ++r) pexp[r] = exp2f(st[r] - mrow);
    float s0 = (pexp[0] + pexp[1]) + (pexp[2] + pexp[3]);
    float s1 = (pexp[4] + pexp[5]) + (pexp[6] + pexp[7]);
    float s2 = (pexp[8] + pexp[9]) + (pexp[10] + pexp[11]);
    float s3 = (pexp[12] + pexp[13]) + (pexp[14] + pexp[15]);
    float rs = (s0 + s1) + (s2 + s3);
    rs += __shfl_xor(rs, 32);
    lrow += rs;
    // ---- pack P to bf16 pairs ----
    unsigned pk[8];
#pragma unroll
    for (int j = 0; j < 8; ++j)
      pk[j] = (unsigned)(unsigned short)f2bf(pexp[2 * j]) |
              ((unsigned)(unsigned short)f2bf(pexp[2 * j + 1]) << 16);
    // ---- permlane32_swap: build PV B-fragments (P^T) ----
    iv2 sA = __builtin_amdgcn_permlane32_swap((int)pk[0], (int)pk[2], false, false);
    iv2 sB = __builtin_amdgcn_permlane32_swap((int)pk[1], (int)pk[3], false, false);
    iv2 sC = __builtin_amdgcn_permlane32_swap((int)pk[4], (int)pk[6], false, false);
    iv2 sD = __builtin_amdgcn_permlane32_swap((int)pk[5], (int)pk[7], false, false);
    iv4 w1 = { sA.x, sB.x, sA.y, sB.y };   // kv0..kv0+15
    iv4 w2 = { sC.x, sD.x, sC.y, sD.y };   // kv0+16..kv0+31
    short8 pb1 = __builtin_bit_cast(short8, w1);
    short8 pb2 = __builtin_bit_cast(short8, w2);
    // ---- PV: OT[d][q] += V^T P^T ----
#pragma unroll
    for (int dblk = 0; dblk < 4; ++dblk) {
      ot[dblk] = __builtin_amdgcn_mfma_f32_32x32x16_bf16(va[dblk * 2],     pb1, ot[dblk], 0, 0, 0);
      ot[dblk] = __builtin_amdgcn_mfma_f32_32x32x16_bf16(va[dblk * 2 + 1], pb2, ot[dblk], 0, 0, 0);
    }
  }

  // ---- epilogue: normalize, transpose via LDS, coalesced store ----
  float inv = 1.0f / lrow;
#pragma unroll
  for (int dblk = 0; dblk < 4; ++dblk) {
#pragma unroll
    for (int rp = 0; rp < 8; ++rp) {
      int r = rp * 2;
      float x0 = ot[dblk][r] * inv;
      float x1 = ot[dblk][r + 1] * inv;
      unsigned pw = (unsigned)(unsigned short)f2bf(x0) |
                    ((unsigned)(unsigned short)f2bf(x1) << 16);
      int d0 = dblk * 32 + (r & 3) + 8 * (r >> 2) + 4 * hi;
      *(unsigned*)(Olds + l31 * 132 + d0) = pw;
    }
  }
  asm volatile("s_waitcnt lgkmcnt(0)" ::: "memory");
  __builtin_amdgcn_sched_barrier(0);
  short* Ob = AObf + ((size_t)b * 1024 + q0) * 2048 + h * 128;
#pragma unroll
  for (int i = 0; i < 8; ++i) {
    int row = i * 4 + (lane >> 4);
    int c8 = (lane & 15) * 8;
    short8 vv = *(const short8*)(Olds + row * 132 + c8);
    *(short8*)(Ob + (size_t)row * 2048 + c8) = vv;
  }
}

// ---------------------------------------------------------------------------
// Launch
// ---------------------------------------------------------------------------
extern "C" void kernel_launch(void* const* d_in, const int* in_sizes, int n_in,
                              void* d_out, int out_size, void* d_ws, size_t ws_size,
                              hipStream_t stream) {
  (void)in_sizes; (void)n_in; (void)out_size; (void)ws_size;
  const float* x    = (const float*)d_in[0];
  const float* q_w  = (const float*)d_in[1];
  const float* q_b  = (const float*)d_in[2];
  const float* k_w  = (const float*)d_in[3];
  const float* k_b  = (const float*)d_in[4];
  const float* v_w  = (const float*)d_in[5];
  const float* v_b  = (const float*)d_in[6];
  const float* o_w  = (const float*)d_in[7];
  const float* cosT = (const float*)d_in[8];
  const float* sinT = (const float*)d_in[9];
  const float* kvbuf = (const float*)d_in[10];
  // d_in[11] = select_index: arange(B*S) -> identity row mapping

  float* out = (float*)d_out;                        // 4*1024*2048 fp32
  float* buf = out + (size_t)4 * 1024 * 2048;        // 8192*4*128 fp32

  char* ws = (char*)d_ws;
  short* Wqkv = (short*)(ws);                        // 10,485,760 B
  short* Wo   = (short*)(ws + 10485760);             //  8,388,608 B
  float* bias = (float*)(ws + 18874368);             // 2560 fp32
  short* Xbf  = (short*)(ws + 18884608);             // 16,777,216 B
  float* QKVf = (float*)(ws + 35661824);             // 41,943,040 B
  short* Kbf  = (short*)(ws + 77604864);             // 2,097,152 B
  short* Vt   = (short*)(ws + 79702016);             // 2,097,152 B
  short* Qbf  = Xbf;                                 // alias: x consumed by gemm1
  short* AObf = (short*)QKVf;                        // alias: QKVf consumed by rope

  hipMemcpyAsync(buf, kvbuf, (size_t)4194304 * 4, hipMemcpyDeviceToDevice, stream);

  pack_wqkv<<<5120, 256, 0, stream>>>(q_w, k_w, v_w, Wqkv);
  pack_bias<<<10, 256, 0, stream>>>(q_b, k_b, v_b, bias);
  cvt_bf16<<<8192, 256, 0, stream>>>(x, Xbf, 2097152);
  cvt_bf16<<<4096, 256, 0, stream>>>(o_w, Wo, 1048576);

  gemm_bt<<<dim3(20, 32), 256, 0, stream>>>(Xbf, Wqkv, bias, QKVf, 4096, 2560, 2048);
  rope_scatter<<<4096, 256, 0, stream>>>(QKVf, cosT, sinT, buf, Qbf, Kbf, Vt);
  attn_kernel<<<dim3(8, 16, 4), 256, 0, stream>>>(Qbf, Kbf, Vt, AObf);
  gemm_bt<<<dim3(16, 32), 256, 0, stream>>>(AObf, Wo, nullptr, out, 4096, 2048, 2048);
}